// Round 2
// baseline (223.751 us; speedup 1.0000x reference)
//
#include <hip/hip_runtime.h>
#include <hip/hip_bf16.h>

typedef unsigned long long u64;
typedef unsigned int u32;
typedef unsigned short u16;

#define C_DIM 128
#define H_NUM 4
#define D_DIM 32
#define MAXN 1024  // max unique neighbors per row handled; E[deg]~32, Poisson tail << 1024

__global__ __launch_bounds__(256) void zero_bm(u64* bm, int nwords) {
    int i = blockIdx.x * 256 + threadIdx.x;
    if (i < nwords) bm[i] = 0ull;
}

__global__ __launch_bounds__(256) void build_bm(const int* __restrict__ row,
                                                const int* __restrict__ col,
                                                int E, int wpr, u64* __restrict__ bm) {
    int e = blockIdx.x * 256 + threadIdx.x;
    if (e < E) {
        int r = row[e];
        int c = col[e];
        atomicOr(&bm[(size_t)r * wpr + (c >> 6)], 1ull << (c & 63));
    }
}

// q,k,v = x @ W^T + b (all three fused). 8 rows per block, 128 threads (thread j = out col j).
__global__ __launch_bounds__(128) void qkv_kernel(
    const float* __restrict__ x,
    const float* __restrict__ wq, const float* __restrict__ bq,
    const float* __restrict__ wk, const float* __restrict__ bk,
    const float* __restrict__ wv, const float* __restrict__ bv,
    float* __restrict__ q, float* __restrict__ k, float* __restrict__ v)
{
    const int ROWS = 8;
    int n0 = blockIdx.x * ROWS;
    int j = threadIdx.x;
    __shared__ float xs[ROWS][C_DIM];
    for (int r = 0; r < ROWS; ++r)
        xs[r][j] = x[(size_t)(n0 + r) * C_DIM + j];
    __syncthreads();
    float aq[ROWS], ak[ROWS], av[ROWS];
    float bqj = bq[j], bkj = bk[j], bvj = bv[j];
    for (int r = 0; r < ROWS; ++r) { aq[r] = bqj; ak[r] = bkj; av[r] = bvj; }
    const float* wqr = wq + (size_t)j * C_DIM;
    const float* wkr = wk + (size_t)j * C_DIM;
    const float* wvr = wv + (size_t)j * C_DIM;
    for (int c = 0; c < C_DIM; c += 4) {
        float4 a4 = *(const float4*)(wqr + c);
        float4 b4 = *(const float4*)(wkr + c);
        float4 c4 = *(const float4*)(wvr + c);
        float wqf[4] = {a4.x, a4.y, a4.z, a4.w};
        float wkf[4] = {b4.x, b4.y, b4.z, b4.w};
        float wvf[4] = {c4.x, c4.y, c4.z, c4.w};
        #pragma unroll
        for (int cc = 0; cc < 4; ++cc) {
            #pragma unroll
            for (int r = 0; r < ROWS; ++r) {
                float xv = xs[r][c + cc];
                aq[r] += xv * wqf[cc];
                ak[r] += xv * wkf[cc];
                av[r] += xv * wvf[cc];
            }
        }
    }
    for (int r = 0; r < ROWS; ++r) {
        size_t o = (size_t)(n0 + r) * C_DIM + j;
        q[o] = aq[r]; k[o] = ak[r]; v[o] = av[r];
    }
}

// One block (256 thr) per target row n: scan bitmap row for unique neighbors,
// score 4 heads per neighbor, softmax per head (wave h = head h), PV gather.
__global__ __launch_bounds__(256) void attn_kernel(
    const float* __restrict__ q, const float* __restrict__ k,
    const float* __restrict__ v, const u16* __restrict__ bm16,
    float* __restrict__ out, int chunks_per_row)
{
    int n = blockIdx.x;
    int t = threadIdx.x;
    __shared__ float qs[C_DIM];
    __shared__ int lm[MAXN];
    __shared__ float ls[H_NUM][MAXN];
    __shared__ int cnt;
    if (t == 0) cnt = 0;
    if (t < C_DIM) qs[t] = q[(size_t)n * C_DIM + t];
    __syncthreads();
    const float scale = 0.17677669529663687f; // 1/sqrt(32)
    u32 w = (t < chunks_per_row) ? (u32)bm16[(size_t)n * chunks_per_row + t] : 0u;
    while (w) {
        int b = __ffs(w) - 1;
        w &= w - 1;
        int m = t * 16 + b;
        const float* kr = k + (size_t)m * C_DIM;
        float s0 = 0.f, s1 = 0.f, s2 = 0.f, s3 = 0.f;
        #pragma unroll
        for (int d = 0; d < D_DIM; d += 4) {
            float4 k0 = *(const float4*)(kr + d);
            float4 k1 = *(const float4*)(kr + 32 + d);
            float4 k2 = *(const float4*)(kr + 64 + d);
            float4 k3 = *(const float4*)(kr + 96 + d);
            s0 += qs[d] * k0.x + qs[d + 1] * k0.y + qs[d + 2] * k0.z + qs[d + 3] * k0.w;
            s1 += qs[32 + d] * k1.x + qs[33 + d] * k1.y + qs[34 + d] * k1.z + qs[35 + d] * k1.w;
            s2 += qs[64 + d] * k2.x + qs[65 + d] * k2.y + qs[66 + d] * k2.z + qs[67 + d] * k2.w;
            s3 += qs[96 + d] * k3.x + qs[97 + d] * k3.y + qs[98 + d] * k3.z + qs[99 + d] * k3.w;
        }
        int jj = atomicAdd(&cnt, 1);
        if (jj < MAXN) {
            lm[jj] = m;
            ls[0][jj] = s0 * scale; ls[1][jj] = s1 * scale;
            ls[2][jj] = s2 * scale; ls[3][jj] = s3 * scale;
        }
    }
    __syncthreads();
    int c = cnt < MAXN ? cnt : MAXN;
    int h = t >> 6, lane = t & 63;
    float mx = -1e30f;
    for (int jj = lane; jj < c; jj += 64) mx = fmaxf(mx, ls[h][jj]);
    #pragma unroll
    for (int off = 32; off; off >>= 1) mx = fmaxf(mx, __shfl_xor(mx, off));
    float sum = 0.f;
    for (int jj = lane; jj < c; jj += 64) {
        float e = __expf(ls[h][jj] - mx);
        ls[h][jj] = e;
        sum += e;
    }
    #pragma unroll
    for (int off = 32; off; off >>= 1) sum += __shfl_xor(sum, off);
    __syncthreads();
    float inv = 1.0f / sum;  // >=1 neighbor guaranteed (self-loops)
    if (lane < D_DIM) {
        float acc = 0.f;
        const float* vb = v + (size_t)h * D_DIM + lane;
        for (int jj = 0; jj < c; ++jj)
            acc += ls[h][jj] * vb[(size_t)lm[jj] * C_DIM];
        out[(size_t)n * C_DIM + h * D_DIM + lane] = acc * inv;
    }
}

// y = x + ao @ wo^T + bo; then LayerNorm(y)*gamma+beta -> f32 out. 8 rows/block.
__global__ __launch_bounds__(128) void oproj_ln_kernel(
    const float* __restrict__ ao, const float* __restrict__ wo, const float* __restrict__ bo,
    const float* __restrict__ x, const float* __restrict__ gamma, const float* __restrict__ beta,
    float* __restrict__ out)
{
    const int ROWS = 8;
    int n0 = blockIdx.x * ROWS;
    int j = threadIdx.x;
    __shared__ float as[ROWS][C_DIM];
    for (int r = 0; r < ROWS; ++r)
        as[r][j] = ao[(size_t)(n0 + r) * C_DIM + j];
    __syncthreads();
    float acc[ROWS];
    float boj = bo[j];
    for (int r = 0; r < ROWS; ++r) acc[r] = boj;
    const float* wr = wo + (size_t)j * C_DIM;
    for (int c = 0; c < C_DIM; c += 4) {
        float4 w4 = *(const float4*)(wr + c);
        float wf[4] = {w4.x, w4.y, w4.z, w4.w};
        #pragma unroll
        for (int cc = 0; cc < 4; ++cc) {
            #pragma unroll
            for (int r = 0; r < ROWS; ++r)
                acc[r] += as[r][c + cc] * wf[cc];
        }
    }
    for (int r = 0; r < ROWS; ++r)
        acc[r] += x[(size_t)(n0 + r) * C_DIM + j];
    // LayerNorm over 128 cols (2 waves)
    int wid = j >> 6, lane = j & 63;
    __shared__ float redS[ROWS][2], redS2[ROWS][2];
    for (int r = 0; r < ROWS; ++r) {
        float s = acc[r], s2 = acc[r] * acc[r];
        #pragma unroll
        for (int off = 32; off; off >>= 1) {
            s += __shfl_xor(s, off);
            s2 += __shfl_xor(s2, off);
        }
        if (lane == 0) { redS[r][wid] = s; redS2[r][wid] = s2; }
    }
    __syncthreads();
    float gj = gamma[j], bj = beta[j];
    for (int r = 0; r < ROWS; ++r) {
        float S = redS[r][0] + redS[r][1];
        float S2 = redS2[r][0] + redS2[r][1];
        float mu = S * (1.0f / C_DIM);
        float var = S2 * (1.0f / C_DIM) - mu * mu;
        float rr = rsqrtf(var + 1e-5f);
        out[(size_t)(n0 + r) * C_DIM + j] = (acc[r] - mu) * rr * gj + bj;
    }
}

extern "C" void kernel_launch(void* const* d_in, const int* in_sizes, int n_in,
                              void* d_out, int out_size, void* d_ws, size_t ws_size,
                              hipStream_t stream)
{
    const float* x     = (const float*)d_in[0];
    const int*   ei    = (const int*)d_in[1];
    const float* wq    = (const float*)d_in[2];
    const float* bq    = (const float*)d_in[3];
    const float* wk    = (const float*)d_in[4];
    const float* bk    = (const float*)d_in[5];
    const float* wv    = (const float*)d_in[6];
    const float* bv    = (const float*)d_in[7];
    const float* wo    = (const float*)d_in[8];
    const float* bo    = (const float*)d_in[9];
    const float* gamma = (const float*)d_in[10];
    const float* beta  = (const float*)d_in[11];
    float* out = (float*)d_out;

    int N = in_sizes[0] / C_DIM;   // 4096
    int E = in_sizes[1] / 2;       // 131072
    int wpr = N >> 6;              // u64 bitmap words per row (64)
    int cpr = N >> 4;              // u16 chunks per row (256)

    size_t mat_bytes = (size_t)N * C_DIM * sizeof(float);  // 2 MiB each
    char* base = (char*)d_ws;
    float* q  = (float*)(base);
    float* k  = (float*)(base + mat_bytes);
    float* v  = (float*)(base + 2 * mat_bytes);
    float* ao = (float*)(base + 3 * mat_bytes);
    u64*   bm = (u64*)(base + 4 * mat_bytes);              // N*N bits = 2 MiB

    int nwords = N * wpr;
    zero_bm<<<(nwords + 255) / 256, 256, 0, stream>>>(bm, nwords);
    build_bm<<<(E + 255) / 256, 256, 0, stream>>>(ei, ei + E, E, wpr, bm);
    qkv_kernel<<<N / 8, 128, 0, stream>>>(x, wq, bq, wk, bk, wv, bv, q, k, v);
    attn_kernel<<<N, 256, 0, stream>>>(q, k, v, (const u16*)bm, ao, cpr);
    oproj_ln_kernel<<<N / 8, 128, 0, stream>>>(ao, wo, bo, x, gamma, beta, out);
}

// Round 4
// 144.330 us; speedup vs baseline: 1.5503x; 1.5503x over previous
//
#include <hip/hip_runtime.h>

typedef unsigned long long u64;
typedef unsigned int u32;
typedef unsigned short u16;

#define C_DIM 128
#define D_DIM 32
#define MAXN 256   // max unique neighbors/row; deg ~ Binom(131072,1/4096): mean 32, max ~60

__global__ __launch_bounds__(256) void zero_bm(u64* bm, int nwords) {
    int i = blockIdx.x * 256 + threadIdx.x;
    if (i < nwords) bm[i] = 0ull;
}

__global__ __launch_bounds__(256) void build_bm(const int* __restrict__ row,
                                                const int* __restrict__ col,
                                                int E, int wpr, u64* __restrict__ bm) {
    int e = blockIdx.x * 256 + threadIdx.x;
    if (e < E) {
        int r = row[e];
        int c = col[e];
        atomicOr(&bm[(size_t)r * wpr + (c >> 6)], 1ull << (c & 63));
    }
}

// q,k,v = x @ W^T + b. 16 rows/block, 256 threads. W staged to LDS (coalesced),
// register tile: 4 strided j-cols x 2 rows per thread.
__global__ __launch_bounds__(256, 2) void qkv_kernel(
    const float* __restrict__ x,
    const float* __restrict__ wq, const float* __restrict__ bq,
    const float* __restrict__ wk, const float* __restrict__ bk,
    const float* __restrict__ wv, const float* __restrict__ bv,
    float* __restrict__ qo, float* __restrict__ ko, float* __restrict__ vo)
{
    const int ROWS = 16;
    const int WSTR = C_DIM + 4;               // 132: b128-aligned padding
    __shared__ float xs[ROWS][C_DIM];         // 8 KB
    __shared__ float wt[C_DIM * WSTR];        // 66 KB, reused for q/k/v weights
    int t = threadIdx.x;
    int n0 = blockIdx.x * ROWS;
    #pragma unroll
    for (int i = 0; i < 2; ++i) {
        int g = t + i * 256;                  // float4 id over 512
        int r = g >> 5, c4 = (g & 31) << 2;
        *(float4*)&xs[r][c4] = *(const float4*)(x + (size_t)(n0 + r) * C_DIM + c4);
    }
    int jg = t & 31;                          // j = jg + 32*jj
    int r0 = (t >> 5) * 2;
    const float* Wp[3] = {wq, wk, wv};
    const float* Bp[3] = {bq, bk, bv};
    float*       Op[3] = {qo, ko, vo};
    for (int s = 0; s < 3; ++s) {
        __syncthreads();                      // previous-pass readers done
        const float* W = Wp[s];
        #pragma unroll
        for (int i = 0; i < 16; ++i) {
            int g = t + i * 256;              // float4 id over 4096
            int j = g >> 5, c4 = (g & 31) << 2;
            *(float4*)&wt[j * WSTR + c4] = *(const float4*)(W + (size_t)j * C_DIM + c4);
        }
        __syncthreads();
        const float* B = Bp[s];
        float acc[4][2];
        #pragma unroll
        for (int jj = 0; jj < 4; ++jj) {
            float b = B[jg + jj * 32];
            acc[jj][0] = b; acc[jj][1] = b;
        }
        for (int c = 0; c < C_DIM; c += 4) {
            float4 xa = *(const float4*)&xs[r0][c];
            float4 xb = *(const float4*)&xs[r0 + 1][c];
            #pragma unroll
            for (int jj = 0; jj < 4; ++jj) {
                float4 w4 = *(const float4*)&wt[(jg + jj * 32) * WSTR + c];
                acc[jj][0] += w4.x * xa.x + w4.y * xa.y + w4.z * xa.z + w4.w * xa.w;
                acc[jj][1] += w4.x * xb.x + w4.y * xb.y + w4.z * xb.z + w4.w * xb.w;
            }
        }
        float* O = Op[s];
        #pragma unroll
        for (int jj = 0; jj < 4; ++jj) {
            int j = jg + jj * 32;
            O[(size_t)(n0 + r0) * C_DIM + j]     = acc[jj][0];
            O[(size_t)(n0 + r0 + 1) * C_DIM + j] = acc[jj][1];
        }
    }
}

// One block (4 waves) per row n. Phase 1: bitmap -> neighbor list (LDS).
// Phase 2: wave-per-neighbor coalesced k gather + shfl reduce -> 4 head scores.
// Phase 3: per-head softmax (wave h). Phase 4: lane=dim coalesced v gather.
__global__ __launch_bounds__(256) void attn_kernel(
    const float* __restrict__ q, const float* __restrict__ k,
    const float* __restrict__ v, const u16* __restrict__ bm16,
    float* __restrict__ out, int chunks_per_row)
{
    int n = blockIdx.x;
    int t = threadIdx.x;
    __shared__ float qs[C_DIM];
    __shared__ int lm[MAXN];
    __shared__ float ls[4][MAXN];
    __shared__ float po[2][C_DIM];
    __shared__ float sminv[4];
    __shared__ int cnt;
    if (t == 0) cnt = 0;
    if (t < C_DIM) qs[t] = q[(size_t)n * C_DIM + t];
    __syncthreads();
    u32 w = (t < chunks_per_row) ? (u32)bm16[(size_t)n * chunks_per_row + t] : 0u;
    while (w) {
        int b = __ffs(w) - 1;
        w &= w - 1;
        int idx = atomicAdd(&cnt, 1);
        if (idx < MAXN) lm[idx] = t * 16 + b;
    }
    __syncthreads();
    int c = cnt < MAXN ? cnt : MAXN;
    int wave = t >> 6, lane = t & 63;
    const float scale = 0.17677669529663687f;  // 1/sqrt(32)
    for (int jj = wave; jj < c; jj += 4) {
        const float* kr = k + (size_t)lm[jj] * C_DIM;
        float p0 = qs[lane] * kr[lane];            // dims 0-63  -> heads 0,1
        float p1 = qs[64 + lane] * kr[64 + lane];  // dims 64-127-> heads 2,3
        #pragma unroll
        for (int off = 16; off; off >>= 1) {
            p0 += __shfl_xor(p0, off);
            p1 += __shfl_xor(p1, off);
        }
        if (lane == 0)       { ls[0][jj] = p0 * scale; ls[2][jj] = p1 * scale; }
        else if (lane == 32) { ls[1][jj] = p0 * scale; ls[3][jj] = p1 * scale; }
    }
    __syncthreads();
    {   // softmax, head = wave
        int h = wave;
        float mx = -1e30f;
        for (int jj = lane; jj < c; jj += 64) mx = fmaxf(mx, ls[h][jj]);
        #pragma unroll
        for (int off = 32; off; off >>= 1) mx = fmaxf(mx, __shfl_xor(mx, off));
        float sum = 0.f;
        for (int jj = lane; jj < c; jj += 64) {
            float e = __expf(ls[h][jj] - mx);
            ls[h][jj] = e;
            sum += e;
        }
        #pragma unroll
        for (int off = 32; off; off >>= 1) sum += __shfl_xor(sum, off);
        if (lane == 0) sminv[h] = 1.0f / sum;   // >=1 neighbor (self-loop)
    }
    __syncthreads();
    {   // PV: d = t&127, neighbor partition = t>>7
        int d = t & 127, part = t >> 7, h = d >> 5;
        float acc = 0.f;
        for (int jj = part; jj < c; jj += 2)
            acc += ls[h][jj] * v[(size_t)lm[jj] * C_DIM + d];
        po[part][d] = acc;
    }
    __syncthreads();
    if (t < C_DIM)
        out[(size_t)n * C_DIM + t] = (po[0][t] + po[1][t]) * sminv[t >> 5];
}

// y = x + ao @ wo^T + bo; LayerNorm(y)*gamma+beta. Same tiling as qkv + fused LN.
__global__ __launch_bounds__(256, 2) void oproj_ln_kernel(
    const float* __restrict__ ao, const float* __restrict__ wo, const float* __restrict__ bo,
    const float* __restrict__ x, const float* __restrict__ gamma, const float* __restrict__ beta,
    float* __restrict__ out)
{
    const int ROWS = 16;
    const int WSTR = C_DIM + 4;
    __shared__ float xs[ROWS][C_DIM];     // ao rows, later y rows
    __shared__ float wt[C_DIM * WSTR];
    int t = threadIdx.x;
    int n0 = blockIdx.x * ROWS;
    #pragma unroll
    for (int i = 0; i < 2; ++i) {
        int g = t + i * 256;
        int r = g >> 5, c4 = (g & 31) << 2;
        *(float4*)&xs[r][c4] = *(const float4*)(ao + (size_t)(n0 + r) * C_DIM + c4);
    }
    #pragma unroll
    for (int i = 0; i < 16; ++i) {
        int g = t + i * 256;
        int j = g >> 5, c4 = (g & 31) << 2;
        *(float4*)&wt[j * WSTR + c4] = *(const float4*)(wo + (size_t)j * C_DIM + c4);
    }
    __syncthreads();
    int jg = t & 31, r0 = (t >> 5) * 2;
    float acc[4][2];
    #pragma unroll
    for (int jj = 0; jj < 4; ++jj) {
        float b = bo[jg + jj * 32];
        acc[jj][0] = b; acc[jj][1] = b;
    }
    for (int c = 0; c < C_DIM; c += 4) {
        float4 xa = *(const float4*)&xs[r0][c];
        float4 xb = *(const float4*)&xs[r0 + 1][c];
        #pragma unroll
        for (int jj = 0; jj < 4; ++jj) {
            float4 w4 = *(const float4*)&wt[(jg + jj * 32) * WSTR + c];
            acc[jj][0] += w4.x * xa.x + w4.y * xa.y + w4.z * xa.z + w4.w * xa.w;
            acc[jj][1] += w4.x * xb.x + w4.y * xb.y + w4.z * xb.z + w4.w * xb.w;
        }
    }
    __syncthreads();   // all xs reads done before overwrite
    #pragma unroll
    for (int jj = 0; jj < 4; ++jj) {
        int j = jg + jj * 32;
        xs[r0][j]     = acc[jj][0] + x[(size_t)(n0 + r0) * C_DIM + j];
        xs[r0 + 1][j] = acc[jj][1] + x[(size_t)(n0 + r0 + 1) * C_DIM + j];
    }
    __syncthreads();
    // LN: wave w handles rows 4w .. 4w+3  (4 waves x 4 rows = all 16 rows)
    int wave = t >> 6, lane = t & 63;
    #pragma unroll
    for (int rr = 0; rr < 4; ++rr) {
        int r = wave * 4 + rr;
        float y0 = xs[r][lane], y1 = xs[r][64 + lane];
        float s = y0 + y1, s2 = y0 * y0 + y1 * y1;
        #pragma unroll
        for (int off = 32; off; off >>= 1) {
            s  += __shfl_xor(s, off);
            s2 += __shfl_xor(s2, off);
        }
        float mu = s * (1.0f / 128.0f);
        float var = s2 * (1.0f / 128.0f) - mu * mu;
        float rstd = rsqrtf(var + 1e-5f);
        size_t o = (size_t)(n0 + r) * C_DIM;
        out[o + lane]      = (y0 - mu) * rstd * gamma[lane] + beta[lane];
        out[o + 64 + lane] = (y1 - mu) * rstd * gamma[64 + lane] + beta[64 + lane];
    }
}

extern "C" void kernel_launch(void* const* d_in, const int* in_sizes, int n_in,
                              void* d_out, int out_size, void* d_ws, size_t ws_size,
                              hipStream_t stream)
{
    const float* x     = (const float*)d_in[0];
    const int*   ei    = (const int*)d_in[1];
    const float* wq    = (const float*)d_in[2];
    const float* bq    = (const float*)d_in[3];
    const float* wk    = (const float*)d_in[4];
    const float* bk    = (const float*)d_in[5];
    const float* wv    = (const float*)d_in[6];
    const float* bv    = (const float*)d_in[7];
    const float* wo    = (const float*)d_in[8];
    const float* bo    = (const float*)d_in[9];
    const float* gamma = (const float*)d_in[10];
    const float* beta  = (const float*)d_in[11];
    float* out = (float*)d_out;

    int N = in_sizes[0] / C_DIM;   // 4096
    int E = in_sizes[1] / 2;       // 131072
    int wpr = N >> 6;              // u64 words per bitmap row
    int cpr = N >> 4;              // u16 chunks per bitmap row

    size_t mat_bytes = (size_t)N * C_DIM * sizeof(float);  // 2 MiB each
    char* base = (char*)d_ws;
    float* q  = (float*)(base);
    float* k  = (float*)(base + mat_bytes);
    float* v  = (float*)(base + 2 * mat_bytes);
    float* ao = (float*)(base + 3 * mat_bytes);
    u64*   bm = (u64*)(base + 4 * mat_bytes);              // N*N bits = 2 MiB

    int nwords = N * wpr;
    zero_bm<<<(nwords + 255) / 256, 256, 0, stream>>>(bm, nwords);
    build_bm<<<(E + 255) / 256, 256, 0, stream>>>(ei, ei + E, E, wpr, bm);
    qkv_kernel<<<N / 16, 256, 0, stream>>>(x, wq, bq, wk, bk, wv, bv, q, k, v);
    attn_kernel<<<N, 256, 0, stream>>>(q, k, v, (const u16*)bm, ao, cpr);
    oproj_ln_kernel<<<N / 16, 256, 0, stream>>>(ao, wo, bo, x, gamma, beta, out);
}